// Round 8
// baseline (376.839 us; speedup 1.0000x reference)
//
#include <hip/hip_runtime.h>

typedef __bf16 bf16x8 __attribute__((ext_vector_type(8)));
typedef float  f32x4  __attribute__((ext_vector_type(4)));

#define NROWS 8192
#define DK    4096
#define MCOLS 4096
#define NKT   64            // K-tiles of BK=64
#define IMG   16384         // bf16 elems per 256x64 tile image (32 KB)
#define X_TILES 32
#define W_TILES 16

#define X_ELEMS ((size_t)NROWS * DK)
#define A_ELEMS ((size_t)MCOLS * DK)
#define WS_NEED ((X_ELEMS + A_ELEMS) * 2)

__device__ __forceinline__ bf16x8 pack8(const float4& a, const float4& b) {
  bf16x8 r;
  r[0] = (__bf16)a.x; r[1] = (__bf16)a.y; r[2] = (__bf16)a.z; r[3] = (__bf16)a.w;
  r[4] = (__bf16)b.x; r[5] = (__bf16)b.y; r[6] = (__bf16)b.z; r[7] = (__bf16)b.w;
  return r;
}

__device__ __forceinline__ void gload16(const __bf16* g, __bf16* l) {
  __builtin_amdgcn_global_load_lds(
      (const __attribute__((address_space(1))) void*)g,
      (__attribute__((address_space(3))) void*)l, 16, 0, 0);
}

// X image: [tm][kt][mfrag 0..15][kc 0..1][lane][8]
__global__ __launch_bounds__(256) void convX(const float* __restrict__ src,
                                             __bf16* __restrict__ dst) {
  const int total = X_TILES * NKT * 2048;
  for (int i = blockIdx.x * blockDim.x + threadIdx.x; i < total;
       i += gridDim.x * blockDim.x) {
    int lane = i & 63;
    int kc   = (i >> 6) & 1;
    int mf   = (i >> 7) & 15;
    int kt   = (i >> 11) & 63;
    int tm   = i >> 17;
    int row = tm * 256 + mf * 16 + (lane & 15);
    int k   = kt * 64 + kc * 32 + (lane >> 4) * 8;
    const float4* p = (const float4*)(src + (size_t)row * DK + k);
    float4 a = p[0], b = p[1];
    *(bf16x8*)(dst + (size_t)i * 8) = pack8(a, b);
  }
}

// W image: [tn][kt][r 0..1][s 0..15][lane][8]; s: kc=s&1, n4=(s>>1)&3, wq=s>>3
__global__ __launch_bounds__(256) void convW(const float* __restrict__ src,
                                             __bf16* __restrict__ dst) {
  const int total = W_TILES * NKT * 2048;
  for (int i = blockIdx.x * blockDim.x + threadIdx.x; i < total;
       i += gridDim.x * blockDim.x) {
    int lane = i & 63;
    int s    = (i >> 6) & 15;
    int r    = (i >> 10) & 1;
    int kt   = (i >> 11) & 63;
    int tn   = i >> 17;
    int kc = s & 1, n4 = (s >> 1) & 3, wq = s >> 3;
    int nfrag = wq * 8 + r * 4 + n4;
    int row = tn * 256 + nfrag * 16 + (lane & 15);
    int k   = kt * 64 + kc * 32 + (lane >> 4) * 8;
    const float4* p = (const float4*)(src + (size_t)row * DK + k);
    float4 a = p[0], b = p[1];
    *(bf16x8*)(dst + (size_t)i * 8) = pack8(a, b);
  }
}

// ---- X-in-regs, W 3-ring LDS, phase-pipelined b reads, __syncthreads only --
__global__ __launch_bounds__(512, 2) void gemm11(const __bf16* __restrict__ wsX,
                                                 const __bf16* __restrict__ wsW,
                                                 float* __restrict__ out) {
  __shared__ __align__(16) __bf16 Wls[3 * IMG];   // 96 KB
  __shared__ float rowsum[2][256];

  const int t    = threadIdx.x;
  const int lane = t & 63;
  const int w    = t >> 6;           // 0..7
  const int wr4  = w >> 1;           // rows wr4*64..+63
  const int wc2  = w & 1;            // cols wc2*128..+127
  const int l15  = lane & 15;
  const int lg   = lane >> 4;

  unsigned bid = blockIdx.x;
  unsigned xcd = bid & 7, seq = bid >> 3;
  const int tile_m = (int)((xcd >> 1) * 8 + (seq & 7));    // 0..31
  const int tile_n = (int)((xcd & 1) * 8 + (seq >> 3));    // 0..15

  const __bf16* xbase = wsX + (size_t)tile_m * ((size_t)NKT * IMG);
  const __bf16* wbase = wsW + (size_t)tile_n * ((size_t)NKT * IMG);
  const __bf16* xw = xbase + (size_t)(wr4 * 4) * 1024 + (size_t)lane * 8;

  f32x4 acc[4][8] = {};
  bf16x8 xa[2][2][2], xb[2][2][2];   // [MH][m2][kc]
  bf16x8 bA[4], bB[4];               // one (NH,kc) phase each: 16 VGPR

  auto loadXset = [&](bf16x8 (&x)[2][2][2], int h) {
    const __bf16* p = xw + (size_t)h * IMG;
#pragma unroll
    for (int MH = 0; MH < 2; ++MH)
#pragma unroll
      for (int m2 = 0; m2 < 2; ++m2)
#pragma unroll
        for (int kc = 0; kc < 2; ++kc)
          x[MH][m2][kc] = *(const bf16x8*)(p + ((MH * 2 + m2) * 2 + kc) * 512);
  };

  // read one b phase (NH=r, kc) from a W k-tile buffer
  auto readPh = [&](bf16x8 (&b)[4], const __bf16* buf, int r, int kc) {
#pragma unroll
    for (int n4 = 0; n4 < 4; ++n4)
      b[n4] = *(const bf16x8*)(buf + r * 8192 +
                               ((wc2 * 4 + n4) * 2 + kc) * 512 + lane * 8);
  };

  auto stageW = [&](const __bf16* src, __bf16* dst) {   // one 8192-elem region
    const __bf16* s0 = src + t * 8;
    __bf16* d0 = dst + w * 512;
    gload16(s0, d0);
    gload16(s0 + 4096, d0 + 4096);
  };

  // 16 MFMA: all 4 row-frags x 4 col-frags for one (NH,kc) phase
  auto burst = [&](const bf16x8 (&x)[2][2][2], const bf16x8 (&b)[4],
                   int NH, int kc) {
    __builtin_amdgcn_s_setprio(1);
#pragma unroll
    for (int mm = 0; mm < 4; ++mm)
#pragma unroll
      for (int n4 = 0; n4 < 4; ++n4)
        acc[mm][NH * 4 + n4] = __builtin_amdgcn_mfma_f32_16x16x32_bf16(
            x[mm >> 1][mm & 1][kc], b[n4], acc[mm][NH * 4 + n4], 0, 0, 0);
    __builtin_amdgcn_s_setprio(0);
  };

  // tile(h): enter with bA = (NH0,kc0) of W(h); phases pipelined one ahead.
  auto tile = [&](int h, bf16x8 (&xcur)[2][2][2], bf16x8 (&xnext)[2][2][2]) {
    const __bf16* bufR = Wls + (h % 3) * IMG;
    const __bf16* bufN = Wls + ((h + 1) % 3) * IMG;
    __bf16* bufS = Wls + ((h + 2) % 3) * IMG;
    const __bf16* wsrc = wbase + (size_t)(h + 2) * IMG;
    const bool last = (h == NKT - 1);

    if (!last) loadXset(xnext, h + 1);            // plain loads; compiler-managed
    // p0
    readPh(bB, bufR, 0, 1);
    burst(xcur, bA, 0, 0);
    if (h < NKT - 2) stageW(wsrc, bufS);          // W0(h+2)
    // p1
    readPh(bA, bufR, 1, 0);
    burst(xcur, bB, 0, 1);
    // p2
    readPh(bB, bufR, 1, 1);
    burst(xcur, bA, 1, 0);
    if (h < NKT - 2) stageW(wsrc + 8192, bufS + 8192);   // W1(h+2)
    // p3
    if (!last) readPh(bA, bufN, 0, 0);            // next tile's first phase
    burst(xcur, bB, 1, 1);

    __syncthreads();   // vmcnt(0)+lgkmcnt(0)+barrier: W(h+2) landed, reads done
  };

  // prologue: W(0)->buf0, W(1)->buf1, X(0)->xa
  stageW(wbase,              Wls);
  stageW(wbase + 8192,       Wls + 8192);
  stageW(wbase + IMG,        Wls + IMG);
  stageW(wbase + IMG + 8192, Wls + IMG + 8192);
  loadXset(xa, 0);
  __syncthreads();
  readPh(bA, Wls, 0, 0);     // first phase of W(0)

  for (int h = 0; h < NKT; h += 2) {
    tile(h,     xa, xb);
    tile(h + 1, xb, xa);
  }

  // ---- epilogue: row sums of squares ----
  float v[4][4];
#pragma unroll
  for (int mr = 0; mr < 4; ++mr)
#pragma unroll
    for (int j = 0; j < 4; ++j) {
      float s = 0.f;
#pragma unroll
      for (int nc = 0; nc < 8; ++nc) {
        float c = acc[mr][nc][j];
        s += c * c;
      }
      s += __shfl_xor(s, 1, 64);
      s += __shfl_xor(s, 2, 64);
      s += __shfl_xor(s, 4, 64);
      s += __shfl_xor(s, 8, 64);
      v[mr][j] = s;
    }

  if (l15 == 0) {
#pragma unroll
    for (int mr = 0; mr < 4; ++mr)
#pragma unroll
      for (int j = 0; j < 4; ++j)
        rowsum[wc2][(wr4 * 4 + mr) * 16 + lg * 4 + j] = v[mr][j];
  }
  __syncthreads();

  if (t < 256) {
    float p = rowsum[0][t] + rowsum[1][t];
    atomicAdd(&out[tile_m * 256 + t], p);
  }
}

// ---------------- fallback (direct fp32 path, used only if ws too small) ----
struct Stage {
  float4 x0a, x0b, x1a, x1b;
  float4 a0a, a0b, a1a, a1b;
};

__global__ __launch_bounds__(256) void gemm_rowsq(const float* __restrict__ X,
                                                  const float* __restrict__ A,
                                                  float* __restrict__ out) {
  __shared__ __align__(16) __bf16 Xs[128 * 32];
  __shared__ __align__(16) __bf16 As[128 * 32];
  __shared__ float rowsum[2][128];

  const int t    = threadIdx.x;
  const int lane = t & 63;
  const int wid  = t >> 6;
  const int wr   = wid >> 1;
  const int wc   = wid & 1;
  const int l15  = lane & 15;
  const int lg   = lane >> 4;

  unsigned bid = blockIdx.x;
  unsigned swz = (bid & 7) * 256u + (bid >> 3);
  const int tile_m = swz >> 5;
  const int tile_n = swz & 31;

  const int srow = t >> 2;
  const int sc   = t & 3;
  const int cw   = sc ^ ((t >> 3) & 3);
  const int woff = srow * 32 + cw * 8;

  const float* gx = X + (size_t)(tile_m * 128 + srow) * DK + sc * 8;
  const float* ga = A + (size_t)(tile_n * 128 + srow) * DK + sc * 8;

  const int chA  = lg ^ ((l15 >> 1) & 3);
  const int aoff = (wr * 64 + l15) * 32 + chA * 8;
  const int boff = (wc * 64 + l15) * 32 + chA * 8;

  f32x4 acc[4][4] = {};

  auto load_tile = [&](int kt) {
    Stage s;
    const float* px = gx + kt * 32;
    const float* pa = ga + kt * 32;
    s.x0a = *(const float4*)(px);
    s.x0b = *(const float4*)(px + 4);
    s.x1a = *(const float4*)(px + (size_t)64 * DK);
    s.x1b = *(const float4*)(px + (size_t)64 * DK + 4);
    s.a0a = *(const float4*)(pa);
    s.a0b = *(const float4*)(pa + 4);
    s.a1a = *(const float4*)(pa + (size_t)64 * DK);
    s.a1b = *(const float4*)(pa + (size_t)64 * DK + 4);
    return s;
  };

  auto store_stage = [&](const Stage& s) {
    *(bf16x8*)(Xs + woff)            = pack8(s.x0a, s.x0b);
    *(bf16x8*)(Xs + woff + 64 * 32)  = pack8(s.x1a, s.x1b);
    *(bf16x8*)(As + woff)            = pack8(s.a0a, s.a0b);
    *(bf16x8*)(As + woff + 64 * 32)  = pack8(s.a1a, s.a1b);
  };

  auto compute = [&]() {
    bf16x8 af[4], bfr[4];
#pragma unroll
    for (int m = 0; m < 4; ++m)
      af[m] = *(const bf16x8*)(Xs + aoff + m * 16 * 32);
#pragma unroll
    for (int n = 0; n < 4; ++n)
      bfr[n] = *(const bf16x8*)(As + boff + n * 16 * 32);
#pragma unroll
    for (int m = 0; m < 4; ++m)
#pragma unroll
      for (int n = 0; n < 4; ++n)
        acc[m][n] = __builtin_amdgcn_mfma_f32_16x16x32_bf16(af[m], bfr[n],
                                                            acc[m][n], 0, 0, 0);
  };

  Stage sa = load_tile(0), sb;

  for (int kt = 0; kt < 128; kt += 2) {
    __syncthreads();
    store_stage(sa);
    sb = load_tile(kt + 1);
    __syncthreads();
    compute();
    __syncthreads();
    store_stage(sb);
    if (kt + 2 < 128) sa = load_tile(kt + 2);
    __syncthreads();
    compute();
  }

  float v[4][4];
#pragma unroll
  for (int m = 0; m < 4; ++m)
#pragma unroll
    for (int j = 0; j < 4; ++j) {
      float s = 0.f;
#pragma unroll
      for (int n = 0; n < 4; ++n) {
        float c = acc[m][n][j];
        s += c * c;
      }
      s += __shfl_xor(s, 1, 64);
      s += __shfl_xor(s, 2, 64);
      s += __shfl_xor(s, 4, 64);
      s += __shfl_xor(s, 8, 64);
      v[m][j] = s;
    }

  if (l15 == 0) {
#pragma unroll
    for (int m = 0; m < 4; ++m)
#pragma unroll
      for (int j = 0; j < 4; ++j)
        rowsum[wc][wr * 64 + m * 16 + lg * 4 + j] = v[m][j];
  }
  __syncthreads();

  if (t < 128) {
    float p = rowsum[0][t] + rowsum[1][t];
    atomicAdd(&out[tile_m * 128 + t], p);
  }
}

extern "C" void kernel_launch(void* const* d_in, const int* in_sizes, int n_in,
                              void* d_out, int out_size, void* d_ws, size_t ws_size,
                              hipStream_t stream) {
  const float* x = (const float*)d_in[0];
  const float* A = (const float*)d_in[1];
  float* out = (float*)d_out;

  hipMemsetAsync(out, 0, (size_t)out_size * sizeof(float), stream);

  if (ws_size >= WS_NEED) {
    __bf16* wsX = (__bf16*)d_ws;
    __bf16* wsW = wsX + X_ELEMS;
    hipLaunchKernelGGL(convX, dim3(2048), dim3(256), 0, stream, x, wsX);
    hipLaunchKernelGGL(convW, dim3(2048), dim3(256), 0, stream, A, wsW);
    hipLaunchKernelGGL(gemm11, dim3(512), dim3(512), 0, stream, wsX, wsW, out);
  } else {
    hipLaunchKernelGGL(gemm_rowsq, dim3(2048), dim3(256), 0, stream, x, A, out);
  }
}

// Round 9
// 304.869 us; speedup vs baseline: 1.2361x; 1.2361x over previous
//
#include <hip/hip_runtime.h>

typedef __bf16 bf16x8 __attribute__((ext_vector_type(8)));
typedef float  f32x16 __attribute__((ext_vector_type(16)));

#define NROWS 8192
#define DK    4096
#define MCOLS 4096
#define NKT   64            // K-tiles of BK=64
#define IMG   16384         // bf16 elems per 256x64 tile image (32 KB)
#define X_TILES 32
#define W_TILES 16

#define X_ELEMS ((size_t)NROWS * DK)
#define A_ELEMS ((size_t)MCOLS * DK)
#define WS_NEED ((X_ELEMS + A_ELEMS) * 2)

#define BAR()  do { __builtin_amdgcn_s_barrier(); asm volatile("" ::: "memory"); } while (0)
#define VM0    asm volatile("s_waitcnt vmcnt(0)" ::: "memory")

__device__ __forceinline__ bf16x8 pack8(const float4& a, const float4& b) {
  bf16x8 r;
  r[0] = (__bf16)a.x; r[1] = (__bf16)a.y; r[2] = (__bf16)a.z; r[3] = (__bf16)a.w;
  r[4] = (__bf16)b.x; r[5] = (__bf16)b.y; r[6] = (__bf16)b.z; r[7] = (__bf16)b.w;
  return r;
}

__device__ __forceinline__ void gload16(const __bf16* g, __bf16* l) {
  __builtin_amdgcn_global_load_lds(
      (const __attribute__((address_space(1))) void*)g,
      (__attribute__((address_space(3))) void*)l, 16, 0, 0);
}

// 32x32-fragment-major image: [tile][kt][frag32 0..7][ks 0..3][lane 0..63][8]
// element (lane, j) = src[tile*256 + frag32*32 + (lane&31)][kt*64 + ks*16 + (lane>>5)*8 + j]
// Used for BOTH X (rows) and W (cols == A rows).
__global__ __launch_bounds__(256) void conv32(const float* __restrict__ src,
                                              __bf16* __restrict__ dst,
                                              int ntiles) {
  const int total = ntiles * NKT * 2048;
  for (int i = blockIdx.x * blockDim.x + threadIdx.x; i < total;
       i += gridDim.x * blockDim.x) {
    int lane = i & 63;
    int ks   = (i >> 6) & 3;
    int mf   = (i >> 8) & 7;
    int kt   = (i >> 11) & 63;
    int tm   = i >> 17;
    int row = tm * 256 + mf * 32 + (lane & 31);
    int k   = kt * 64 + ks * 16 + (lane >> 5) * 8;
    const float4* p = (const float4*)(src + (size_t)row * DK + k);
    float4 a = p[0], b = p[1];
    *(bf16x8*)(dst + (size_t)i * 8) = pack8(a, b);
  }
}

// ---- 32x32 MFMA, X-in-regs, W 3-ring LDS, 1 barrier + 1 vmcnt(0) per K-tile
__global__ __launch_bounds__(512, 2) void gemm12(const __bf16* __restrict__ wsX,
                                                 const __bf16* __restrict__ wsW,
                                                 float* __restrict__ out) {
  __shared__ __align__(16) __bf16 Wls[3 * IMG];   // 96 KB ring
  __shared__ float rowsum[2][256];

  const int t    = threadIdx.x;
  const int lane = t & 63;
  const int w    = t >> 6;           // 0..7
  const int wr4  = w >> 1;           // 0..3 : rows wr4*64..+63 (frag32 wr4*2, wr4*2+1)
  const int wc2  = w & 1;            // 0..1 : cols wc2*128..+127 (frag32 wc2*4..+3)
  const int hi   = lane >> 5;        // 0..1

  // XCD L2-window mapping (R5): each XCD owns an 8m x 8n region
  unsigned bid = blockIdx.x;
  unsigned xcd = bid & 7, seq = bid >> 3;
  const int tile_m = (int)((xcd >> 1) * 8 + (seq & 7));    // 0..31
  const int tile_n = (int)((xcd & 1) * 8 + (seq >> 3));    // 0..15

  const __bf16* xbase = wsX + (size_t)tile_m * ((size_t)NKT * IMG);
  const __bf16* wbase = wsW + (size_t)tile_n * ((size_t)NKT * IMG);
  // per-wave X fragment base (frag32 = wr4*2 + mt)
  const __bf16* xw = xbase + ((size_t)(wr4 * 2) * 4) * 512 + (size_t)lane * 8;

  f32x16 acc[2][4] = {};               // [mt][nf] : 128 VGPR
  bf16x8 xa[2][4], xb[2][4];           // [mt][ks] : 32+32 VGPR
  bf16x8 b[4][2];                      // [nf][ks-half] : 32 VGPR

  auto loadX = [&](bf16x8 (&x)[2][4], int h) {       // 8 plain global b128
    const __bf16* p = xw + (size_t)h * IMG;
#pragma unroll
    for (int mt = 0; mt < 2; ++mt)
#pragma unroll
      for (int ks = 0; ks < 4; ++ks)
        x[mt][ks] = *(const bf16x8*)(p + (mt * 4 + ks) * 512);
  };

  auto readB = [&](const __bf16* slot, int kh) {     // 8 ds_read_b128
#pragma unroll
    for (int nf = 0; nf < 4; ++nf)
#pragma unroll
      for (int ks = 0; ks < 2; ++ks)
        b[nf][ks] = *(const bf16x8*)(slot + ((wc2 * 4 + nf) * 4 + kh * 2 + ks) * 512
                                     + lane * 8);
  };

  auto stageW = [&](const __bf16* src, __bf16* dst) {  // 8192 elems, 2 gloads
    const __bf16* s0 = src + t * 8;
    __bf16* d0 = dst + w * 512;
    gload16(s0, d0);
    gload16(s0 + 4096, d0 + 4096);
  };

  auto group = [&](const bf16x8 (&x)[2][4], int kh) { // 16 MFMA (2mt x 4nf x 2ks)
    __builtin_amdgcn_s_setprio(1);
#pragma unroll
    for (int ks = 0; ks < 2; ++ks)
#pragma unroll
      for (int mt = 0; mt < 2; ++mt)
#pragma unroll
        for (int nf = 0; nf < 4; ++nf)
          acc[mt][nf] = __builtin_amdgcn_mfma_f32_32x32x16_bf16(
              x[mt][kh * 2 + ks], b[nf][ks], acc[mt][nf], 0, 0, 0);
    __builtin_amdgcn_s_setprio(0);
  };

  auto tile = [&](int h, bf16x8 (&xcur)[2][4], bf16x8 (&xnext)[2][4]) {
    const __bf16* slotR = Wls + (h % 3) * IMG;
    __bf16* slotS = Wls + ((h + 2) % 3) * IMG;

    readB(slotR, 0);                               // b ks0,1 of W(h)
    if (h + 1 < NKT) loadX(xnext, h + 1);          // plain loads, counted by vmcnt
    if (h + 2 < NKT) {                             // stage W(h+2) -> ring slot
      const __bf16* wsrc = wbase + (size_t)(h + 2) * IMG;
      stageW(wsrc, slotS);
      stageW(wsrc + 8192, slotS + 8192);
    }
    group(xcur, 0);                                // compiler lgkm-waits b
    readB(slotR, 1);                               // b ks2,3
    group(xcur, 1);
    VM0;                                           // all X + W gloads landed
    BAR();                                         // block-wide: slotS ready
  };

  // prologue: W(0)->slot0, W(1)->slot1, X(0)->xa
  stageW(wbase,              Wls);
  stageW(wbase + 8192,       Wls + 8192);
  stageW(wbase + IMG,        Wls + IMG);
  stageW(wbase + IMG + 8192, Wls + IMG + 8192);
  loadX(xa, 0);
  VM0;
  BAR();

  for (int h = 0; h < NKT; h += 2) {
    tile(h,     xa, xb);
    tile(h + 1, xb, xa);
  }

  // ---- epilogue: row sums of squares ----
  // acc[mt][nf] reg r: row = tile_m*256 + (wr4*2+mt)*32 + (r&3) + 8*(r>>2) + 4*hi
  //                    col = (wc2*4+nf)*32 + (lane&31)
  float v[2][16];
#pragma unroll
  for (int mt = 0; mt < 2; ++mt)
#pragma unroll
    for (int r = 0; r < 16; ++r) {
      float s = 0.f;
#pragma unroll
      for (int nf = 0; nf < 4; ++nf) {
        float c = acc[mt][nf][r];
        s += c * c;
      }
      s += __shfl_xor(s, 1, 64);
      s += __shfl_xor(s, 2, 64);
      s += __shfl_xor(s, 4, 64);
      s += __shfl_xor(s, 8, 64);
      s += __shfl_xor(s, 16, 64);
      v[mt][r] = s;
    }

  if ((lane & 31) == 0) {
#pragma unroll
    for (int mt = 0; mt < 2; ++mt)
#pragma unroll
      for (int r = 0; r < 16; ++r)
        rowsum[wc2][(wr4 * 2 + mt) * 32 + (r & 3) + 8 * (r >> 2) + 4 * hi] = v[mt][r];
  }
  __syncthreads();

  if (t < 256) {
    float p = rowsum[0][t] + rowsum[1][t];
    atomicAdd(&out[tile_m * 256 + t], p);
  }
}

// ---------------- fallback (direct fp32 path, used only if ws too small) ----
typedef float f32x4 __attribute__((ext_vector_type(4)));
struct Stage {
  float4 x0a, x0b, x1a, x1b;
  float4 a0a, a0b, a1a, a1b;
};

__global__ __launch_bounds__(256) void gemm_rowsq(const float* __restrict__ X,
                                                  const float* __restrict__ A,
                                                  float* __restrict__ out) {
  __shared__ __align__(16) __bf16 Xs[128 * 32];
  __shared__ __align__(16) __bf16 As[128 * 32];
  __shared__ float rowsum[2][128];

  const int t    = threadIdx.x;
  const int lane = t & 63;
  const int wid  = t >> 6;
  const int wr   = wid >> 1;
  const int wc   = wid & 1;
  const int l15  = lane & 15;
  const int lg   = lane >> 4;

  unsigned bid = blockIdx.x;
  unsigned swz = (bid & 7) * 256u + (bid >> 3);
  const int tile_m = swz >> 5;
  const int tile_n = swz & 31;

  const int srow = t >> 2;
  const int sc   = t & 3;
  const int cw   = sc ^ ((t >> 3) & 3);
  const int woff = srow * 32 + cw * 8;

  const float* gx = X + (size_t)(tile_m * 128 + srow) * DK + sc * 8;
  const float* ga = A + (size_t)(tile_n * 128 + srow) * DK + sc * 8;

  const int chA  = lg ^ ((l15 >> 1) & 3);
  const int aoff = (wr * 64 + l15) * 32 + chA * 8;
  const int boff = (wc * 64 + l15) * 32 + chA * 8;

  f32x4 acc[4][4] = {};

  auto load_tile = [&](int kt) {
    Stage s;
    const float* px = gx + kt * 32;
    const float* pa = ga + kt * 32;
    s.x0a = *(const float4*)(px);
    s.x0b = *(const float4*)(px + 4);
    s.x1a = *(const float4*)(px + (size_t)64 * DK);
    s.x1b = *(const float4*)(px + (size_t)64 * DK + 4);
    s.a0a = *(const float4*)(pa);
    s.a0b = *(const float4*)(pa + 4);
    s.a1a = *(const float4*)(pa + (size_t)64 * DK);
    s.a1b = *(const float4*)(pa + (size_t)64 * DK + 4);
    return s;
  };

  auto store_stage = [&](const Stage& s) {
    *(bf16x8*)(Xs + woff)            = pack8(s.x0a, s.x0b);
    *(bf16x8*)(Xs + woff + 64 * 32)  = pack8(s.x1a, s.x1b);
    *(bf16x8*)(As + woff)            = pack8(s.a0a, s.a0b);
    *(bf16x8*)(As + woff + 64 * 32)  = pack8(s.a1a, s.a1b);
  };

  auto compute = [&]() {
    bf16x8 af[4], bfr[4];
#pragma unroll
    for (int m = 0; m < 4; ++m)
      af[m] = *(const bf16x8*)(Xs + aoff + m * 16 * 32);
#pragma unroll
    for (int n = 0; n < 4; ++n)
      bfr[n] = *(const bf16x8*)(As + boff + n * 16 * 32);
#pragma unroll
    for (int m = 0; m < 4; ++m)
#pragma unroll
      for (int n = 0; n < 4; ++n)
        acc[m][n] = __builtin_amdgcn_mfma_f32_16x16x32_bf16(af[m], bfr[n],
                                                            acc[m][n], 0, 0, 0);
  };

  Stage sa = load_tile(0), sb;

  for (int kt = 0; kt < 128; kt += 2) {
    __syncthreads();
    store_stage(sa);
    sb = load_tile(kt + 1);
    __syncthreads();
    compute();
    __syncthreads();
    store_stage(sb);
    if (kt + 2 < 128) sa = load_tile(kt + 2);
    __syncthreads();
    compute();
  }

  float v[4][4];
#pragma unroll
  for (int m = 0; m < 4; ++m)
#pragma unroll
    for (int j = 0; j < 4; ++j) {
      float s = 0.f;
#pragma unroll
      for (int n = 0; n < 4; ++n) {
        float c = acc[m][n][j];
        s += c * c;
      }
      s += __shfl_xor(s, 1, 64);
      s += __shfl_xor(s, 2, 64);
      s += __shfl_xor(s, 4, 64);
      s += __shfl_xor(s, 8, 64);
      v[m][j] = s;
    }

  if (l15 == 0) {
#pragma unroll
    for (int m = 0; m < 4; ++m)
#pragma unroll
      for (int j = 0; j < 4; ++j)
        rowsum[wc][wr * 64 + m * 16 + lg * 4 + j] = v[m][j];
  }
  __syncthreads();

  if (t < 128) {
    float p = rowsum[0][t] + rowsum[1][t];
    atomicAdd(&out[tile_m * 128 + t], p);
  }
}

extern "C" void kernel_launch(void* const* d_in, const int* in_sizes, int n_in,
                              void* d_out, int out_size, void* d_ws, size_t ws_size,
                              hipStream_t stream) {
  const float* x = (const float*)d_in[0];
  const float* A = (const float*)d_in[1];
  float* out = (float*)d_out;

  hipMemsetAsync(out, 0, (size_t)out_size * sizeof(float), stream);

  if (ws_size >= WS_NEED) {
    __bf16* wsX = (__bf16*)d_ws;
    __bf16* wsW = wsX + X_ELEMS;
    hipLaunchKernelGGL(conv32, dim3(2048), dim3(256), 0, stream, x, wsX, X_TILES);
    hipLaunchKernelGGL(conv32, dim3(2048), dim3(256), 0, stream, A, wsW, W_TILES);
    hipLaunchKernelGGL(gemm12, dim3(512), dim3(512), 0, stream, wsX, wsW, out);
  } else {
    hipLaunchKernelGGL(gemm_rowsq, dim3(2048), dim3(256), 0, stream, x, A, out);
  }
}